// Round 10
// baseline (150.428 us; speedup 1.0000x reference)
//
#include <hip/hip_runtime.h>

#define B_ROWS 2048
#define S_LEN  8192
#define PER_LANE 16
#define CHUNK (64 * PER_LANE)      // 1024 elements per chunk
#define CPW 2                      // adjacent chunks per wave (exact in-reg carry)
#define WPB 4                      // waves per block
#define TPB 256
#define NBLOCKS B_ROWS             // one row per block
#define NPART (NBLOCKS * WPB)      // 8192 per-wave partials
#define HALO 256                   // carry horizon: (1-a)^256 <= 2e-12 for all alphas

typedef float f4 __attribute__((ext_vector_type(4)));

// Un-rematerializable 16B load: the ASM STATEMENT cannot be duplicated, so its
// result MUST stay register-resident (r2-r9: normal loads from __restrict-const
// pointers were legally re-issued by the allocator -> VGPR pinned at 28-52 and
// pass-2 serialized reload latency). This binds the data to VGPRs.
__device__ __forceinline__ f4 gload(const float* p) {
    f4 r;
    unsigned long long a = (unsigned long long)p;
    asm volatile("global_load_dwordx4 %0, %1, off" : "=v"(r) : "v"(a));
    return r;
}
// Drain all loads + scheduling fence (rule #18: consumers can hoist past an
// inline-asm waitcnt; sched_barrier(0) right after is the required fence).
__device__ __forceinline__ void vwait0() {
    asm volatile("s_waitcnt vmcnt(0)" ::: "memory");
    __builtin_amdgcn_sched_barrier(0);
}

// ---- compile-time decay constants ----
constexpr double cpowi(double b, int e) { double r = 1.0; for (int i = 0; i < e; ++i) r *= b; return r; }
constexpr float tof(double x) { return (x < 1.2e-38 && x > -1.2e-38) ? 0.0f : (float)x; }

// Delta-space EMA: du_j = W*du_{j-1} + dx_j  (W = 1-alpha); pd = alpha*du.
#define W0f 0.9f
#define W1f 0.7f
#define W2f 0.4f
#define SE0 0.2f               // 2*alpha (we accumulate 2*h; 0.5 folded into final weights)
#define SE1 0.6f
#define SE2 1.2f
constexpr float NA0 = -(0.1f * 0.1f);   // -alpha^2
constexpr float NA1 = -(0.3f * 0.3f);
constexpr float NA2 = -(0.6f * 0.6f);

// main Kogge-Stone (lane spacing 16); sub-noise steps pruned (validated r2-r9, absmax 0.0)
constexpr float D0_1 = tof(cpowi(0.9, 16)),  D0_2 = tof(cpowi(0.9, 32));
constexpr float D0_4 = tof(cpowi(0.9, 64)),  D0_8 = tof(cpowi(0.9, 128));
constexpr float D1_1 = tof(cpowi(0.7, 16)),  D1_2 = tof(cpowi(0.7, 32));
constexpr float D2_1 = tof(cpowi(0.4, 16));
// halo Kogge-Stone (lane spacing 4)
constexpr float H0_1 = tof(cpowi(0.9, 4)),   H0_2 = tof(cpowi(0.9, 8));
constexpr float H0_4 = tof(cpowi(0.9, 16)),  H0_8 = tof(cpowi(0.9, 32));
constexpr float H0_16 = tof(cpowi(0.9, 64)), H0_32 = tof(cpowi(0.9, 128));
constexpr float H1_1 = tof(cpowi(0.7, 4)),   H1_2 = tof(cpowi(0.7, 8));
constexpr float H1_4 = tof(cpowi(0.7, 16)),  H1_8 = tof(cpowi(0.7, 32));
constexpr float H1_16 = tof(cpowi(0.7, 64));
constexpr float H2_1 = tof(cpowi(0.4, 4)),   H2_2 = tof(cpowi(0.4, 8));
constexpr float H2_4 = tof(cpowi(0.4, 16));

// log2(1-alpha): chunk carry fold weights (1-a)^(16*lane) = exp2(16*lane*log2(1-a))
#define L2_0 (-0.15200309344504997f)
#define L2_1 (-0.51457317282975830f)
#define L2_2 (-1.32192809488736230f)

__device__ __forceinline__ float scan6(float v, int lane, float d1, float d2, float d4,
                                       float d8, float d16, float d32) {
    float u;
    u = __shfl_up(v, 1);  v += (lane >= 1  ? d1  : 0.0f) * u;
    u = __shfl_up(v, 2);  v += (lane >= 2  ? d2  : 0.0f) * u;
    u = __shfl_up(v, 4);  v += (lane >= 4  ? d4  : 0.0f) * u;
    u = __shfl_up(v, 8);  v += (lane >= 8  ? d8  : 0.0f) * u;
    u = __shfl_up(v, 16); v += (lane >= 16 ? d16 : 0.0f) * u;
    u = __shfl_up(v, 32); v += (lane >= 32 ? d32 : 0.0f) * u;
    return v;
}
__device__ __forceinline__ float scan5(float v, int lane, float d1, float d2, float d4,
                                       float d8, float d16) {
    float u;
    u = __shfl_up(v, 1);  v += (lane >= 1  ? d1  : 0.0f) * u;
    u = __shfl_up(v, 2);  v += (lane >= 2  ? d2  : 0.0f) * u;
    u = __shfl_up(v, 4);  v += (lane >= 4  ? d4  : 0.0f) * u;
    u = __shfl_up(v, 8);  v += (lane >= 8  ? d8  : 0.0f) * u;
    u = __shfl_up(v, 16); v += (lane >= 16 ? d16 : 0.0f) * u;
    return v;
}
__device__ __forceinline__ float scan4(float v, int lane, float d1, float d2, float d4, float d8) {
    float u;
    u = __shfl_up(v, 1); v += (lane >= 1 ? d1 : 0.0f) * u;
    u = __shfl_up(v, 2); v += (lane >= 2 ? d2 : 0.0f) * u;
    u = __shfl_up(v, 4); v += (lane >= 4 ? d4 : 0.0f) * u;
    u = __shfl_up(v, 8); v += (lane >= 8 ? d8 : 0.0f) * u;
    return v;
}
__device__ __forceinline__ float scan3(float v, int lane, float d1, float d2, float d4) {
    float u;
    u = __shfl_up(v, 1); v += (lane >= 1 ? d1 : 0.0f) * u;
    u = __shfl_up(v, 2); v += (lane >= 2 ? d2 : 0.0f) * u;
    u = __shfl_up(v, 4); v += (lane >= 4 ? d4 : 0.0f) * u;
    return v;
}
__device__ __forceinline__ float scan2(float v, int lane, float d1, float d2) {
    float u;
    u = __shfl_up(v, 1); v += (lane >= 1 ? d1 : 0.0f) * u;
    u = __shfl_up(v, 2); v += (lane >= 2 ? d2 : 0.0f) * u;
    return v;
}
__device__ __forceinline__ float scan1(float v, int lane, float d1) {
    float u;
    u = __shfl_up(v, 1); v += (lane >= 1 ? d1 : 0.0f) * u;
    return v;
}

__global__ void __launch_bounds__(TPB, 4) msl_main(const float* __restrict__ pred,
                                                   const float* __restrict__ targ,
                                                   float* __restrict__ partial) {
    const int lane = threadIdx.x & 63;
    const int wave = threadIdx.x >> 6;
    const float* __restrict__ prow = pred + (size_t)blockIdx.x * S_LEN;
    const float* __restrict__ trow = targ + (size_t)blockIdx.x * S_LEN;
    const bool lz = (lane == 0);
    const bool w0 = (wave == 0);

    // carry-fold weights, hoisted (lane-only dependence)
    const float e  = (float)(PER_LANE * lane);
    const float G0 = exp2f(e * L2_0);
    const float G1 = exp2f(e * L2_1);
    const float G2 = exp2f(e * L2_2);

    const int co0  = wave * CPW * CHUNK;
    const int base = co0 + lane * PER_LANE;

    // ---- issue ALL loads up front (halo + both chunks = up to 18 dwordx4),
    // then ONE vmcnt(0): a single ~700cy stall per wave instead of 4-5
    // dependent batches; data is pinned in VGPRs by the asm loads. ----
    f4 hp4 = {0.f, 0.f, 0.f, 0.f}, ht4 = {0.f, 0.f, 0.f, 0.f};
    if (wave > 0) {                       // wave-uniform branch
        hp4 = gload(prow + co0 - HALO + lane * 4);
        ht4 = gload(trow + co0 - HALO + lane * 4);
    }
    f4 cpv[CPW][4], ctv[CPW][4];
#pragma unroll
    for (int c = 0; c < CPW; ++c) {
#pragma unroll
        for (int q = 0; q < 4; ++q) {
            cpv[c][q] = gload(prow + base + c * CHUNK + q * 4);
            ctv[c][q] = gload(trow + base + c * CHUNK + q * 4);
        }
    }
    vwait0();

    // ---- halo: recompute the delta-EMA carry from the preceding 256 elements
    // (truncation weight (1-a)^256 <= 2e-12; validated r7/r9, absmax 0.0). ----
    float Cp0 = 0.f, Cp1 = 0.f, Cp2 = 0.f, Ct0 = 0.f, Ct1 = 0.f, Ct2 = 0.f;
    float lastp = 0.f, lastt = 0.f;
    if (wave > 0) {
        float php = __shfl_up(hp4[3], 1);
        float pht = __shfl_up(ht4[3], 1);
        if (lz) { php = hp4[0]; pht = ht4[0]; }   // oldest halo dx := 0 (weight ~0)

        float Ap0 = 0.f, Ap1 = 0.f, Ap2 = 0.f, At0 = 0.f, At1 = 0.f, At2 = 0.f;
#pragma unroll
        for (int s = 0; s < 4; ++s) {
            float dxp = hp4[s] - php; php = hp4[s];
            float dxt = ht4[s] - pht; pht = ht4[s];
            Ap0 = fmaf(W0f, Ap0, dxp);
            Ap1 = fmaf(W1f, Ap1, dxp);
            Ap2 = fmaf(W2f, Ap2, dxp);
            At0 = fmaf(W0f, At0, dxt);
            At1 = fmaf(W1f, At1, dxt);
            At2 = fmaf(W2f, At2, dxt);
        }
        float vh;
        vh = scan6(Ap0, lane, H0_1, H0_2, H0_4, H0_8, H0_16, H0_32); Cp0 = __shfl(vh, 63);
        vh = scan5(Ap1, lane, H1_1, H1_2, H1_4, H1_8, H1_16);        Cp1 = __shfl(vh, 63);
        vh = scan3(Ap2, lane, H2_1, H2_2, H2_4);                     Cp2 = __shfl(vh, 63);
        vh = scan6(At0, lane, H0_1, H0_2, H0_4, H0_8, H0_16, H0_32); Ct0 = __shfl(vh, 63);
        vh = scan5(At1, lane, H1_1, H1_2, H1_4, H1_8, H1_16);        Ct1 = __shfl(vh, 63);
        vh = scan3(At2, lane, H2_1, H2_2, H2_4);                     Ct2 = __shfl(vh, 63);
        lastp = __shfl(hp4[3], 63);
        lastt = __shfl(ht4[3], 63);
    }

    float acc0 = 0.f, acc1 = 0.f, acc2 = 0.f;

    // ---- two adjacent chunks; chunk 1's carry is EXACT (lane-63 pass-2 exit).
    // No barriers, no LDS; dx recomputed in pass 2 from the pinned registers. ----
#pragma unroll
    for (int c = 0; c < CPW; ++c) {
        float xp[PER_LANE], xt[PER_LANE];
#pragma unroll
        for (int j = 0; j < PER_LANE; ++j) {   // register renaming, no ops
            xp[j] = cpv[c][j >> 2][j & 3];
            xt[j] = ctv[c][j >> 2][j & 3];
        }

        // previous element for each lane's first dx
        float pvp = __shfl_up(xp[PER_LANE - 1], 1);
        float pvt = __shfl_up(xt[PER_LANE - 1], 1);
        if (lz) {
            pvp = (w0 && c == 0) ? xp[0] : lastp;   // head: dx_0 = 0
            pvt = (w0 && c == 0) ? xt[0] : lastt;
        }

        // ---- pass 1: lane-local du-EMA on dx, zero carry ----
        float Mp0 = 0.f, Mp1 = 0.f, Mp2 = 0.f, Mt0 = 0.f, Mt1 = 0.f, Mt2 = 0.f;
        float pp = pvp, pt = pvt;
#pragma unroll
        for (int j = 0; j < PER_LANE; ++j) {
            float dxp = xp[j] - pp; pp = xp[j];
            float dxt = xt[j] - pt; pt = xt[j];
            Mp0 = fmaf(W0f, Mp0, dxp);
            Mp1 = fmaf(W1f, Mp1, dxp);
            Mp2 = fmaf(W2f, Mp2, dxp);
            Mt0 = fmaf(W0f, Mt0, dxt);
            Mt1 = fmaf(W1f, Mt1, dxt);
            Mt2 = fmaf(W2f, Mt2, dxt);
        }

        // ---- main scans (spacing 16, pruned) ----
        float vp0 = scan4(Mp0, lane, D0_1, D0_2, D0_4, D0_8);
        float vp1 = scan2(Mp1, lane, D1_1, D1_2);
        float vp2 = scan1(Mp2, lane, D2_1);
        float vt0 = scan4(Mt0, lane, D0_1, D0_2, D0_4, D0_8);
        float vt1 = scan2(Mt1, lane, D1_1, D1_2);
        float vt2 = scan1(Mt2, lane, D2_1);

        // exclusive + carry fold: y_l = (l==0) ? C : v_{l-1} + (1-a)^(16l)*C
        float up0 = __shfl_up(vp0, 1), up1 = __shfl_up(vp1, 1), up2 = __shfl_up(vp2, 1);
        float ut0 = __shfl_up(vt0, 1), ut1 = __shfl_up(vt1, 1), ut2 = __shfl_up(vt2, 1);

        float yp0 = lz ? Cp0 : fmaf(G0, Cp0, up0);
        float yp1 = lz ? Cp1 : fmaf(G1, Cp1, up1);
        float yp2 = lz ? Cp2 : fmaf(G2, Cp2, up2);
        float yt0 = lz ? Ct0 : fmaf(G0, Ct0, ut0);
        float yt1 = lz ? Ct1 : fmaf(G1, Ct1, ut1);
        float yt2 = lz ? Ct2 : fmaf(G2, Ct2, ut2);

        // ---- pass 2: recompute dx from registers, du = fma(W, du, dx),
        // huber on scaled deltas: pd = a*dup, td = a*dut; dir<0 <=> dup*dut<0;
        // se = a|dup-dut|; quad = 0.5*max(1 - a^2*dup*dut, 0)^2. Accumulate 2*h. ----
        const float skip = (w0 && c == 0 && lz) ? 0.0f : 1.0f;
        pp = pvp; pt = pvt;
#pragma unroll
        for (int j = 0; j < PER_LANE; ++j) {
            float dxp = xp[j] - pp; pp = xp[j];
            float dxt = xt[j] - pt; pt = xt[j];
            yp0 = fmaf(W0f, yp0, dxp);
            yt0 = fmaf(W0f, yt0, dxt);
            yp1 = fmaf(W1f, yp1, dxp);
            yt1 = fmaf(W1f, yt1, dxt);
            yp2 = fmaf(W2f, yp2, dxp);
            yt2 = fmaf(W2f, yt2, dxt);

            float m0 = yp0 * yt0, m1 = yp1 * yt1, m2 = yp2 * yt2;
            float se0 = SE0 * fabsf(yp0 - yt0);
            float se1 = SE1 * fabsf(yp1 - yt1);
            float se2 = SE2 * fabsf(yp2 - yt2);
            float mm0 = fmaxf(fmaf(NA0, m0, 1.0f), 0.0f);
            float mm1 = fmaxf(fmaf(NA1, m1, 1.0f), 0.0f);
            float mm2 = fmaxf(fmaf(NA2, m2, 1.0f), 0.0f);
            float h0 = (m0 < 0.0f) ? se0 : mm0 * mm0;
            float h1 = (m1 < 0.0f) ? se1 : mm1 * mm1;
            float h2 = (m2 < 0.0f) ? se2 : mm2 * mm2;
            if (j == 0) { h0 *= skip; h1 *= skip; h2 *= skip; }
            acc0 += h0; acc1 += h1; acc2 += h2;
        }

        // exact carry into the adjacent next chunk (lane-63 exit state)
        if (c + 1 < CPW) {
            Cp0 = __shfl(yp0, 63); Cp1 = __shfl(yp1, 63); Cp2 = __shfl(yp2, 63);
            Ct0 = __shfl(yt0, 63); Ct1 = __shfl(yt1, 63); Ct2 = __shfl(yt2, 63);
            lastp = __shfl(xp[PER_LANE - 1], 63);
            lastt = __shfl(xt[PER_LANE - 1], 63);
        }
    }

    // accumulated 2*h -> weights 0.5*{0.5,0.3,0.2}; wave reduce; per-wave partial
    float wacc = 0.25f * acc0 + 0.15f * acc1 + 0.10f * acc2;
#pragma unroll
    for (int o = 32; o > 0; o >>= 1) wacc += __shfl_down(wacc, o);
    if (lz) partial[blockIdx.x * WPB + wave] = wacc;
}

__global__ void __launch_bounds__(256) msl_reduce(const float* __restrict__ partial,
                                                  float* __restrict__ out) {
    const int tid = threadIdx.x;
    float v = 0.f;
#pragma unroll
    for (int k = 0; k < NPART / 256; ++k) v += partial[tid + 256 * k];
#pragma unroll
    for (int o = 32; o > 0; o >>= 1) v += __shfl_down(v, o);
    __shared__ float s[4];
    if ((tid & 63) == 0) s[tid >> 6] = v;
    __syncthreads();
    if (tid == 0)
        out[0] = (s[0] + s[1] + s[2] + s[3]) *
                 (float)(1.0 / ((double)(S_LEN - 1) * (double)B_ROWS));
}

extern "C" void kernel_launch(void* const* d_in, const int* in_sizes, int n_in,
                              void* d_out, int out_size, void* d_ws, size_t ws_size,
                              hipStream_t stream) {
    const float* pred = (const float*)d_in[0];
    const float* targ = (const float*)d_in[1];
    float* out = (float*)d_out;
    float* partial = (float*)d_ws;  // 8192 floats = 32 KB

    msl_main<<<NBLOCKS, TPB, 0, stream>>>(pred, targ, partial);
    msl_reduce<<<1, 256, 0, stream>>>(partial, out);
}

// Round 11
// 147.585 us; speedup vs baseline: 1.0193x; 1.0193x over previous
//
#include <hip/hip_runtime.h>

#define B_ROWS 2048
#define S_LEN  8192
#define PER_LANE 16
#define CHUNK (64 * PER_LANE)      // 1024 elements per wave-chunk
#define CPR (S_LEN / CHUNK)        // 8 chunks per row
#define TPB 256
#define WPB 4                      // waves per block -- each wave an INDEPENDENT chunk
#define NCHUNK (B_ROWS * CPR)      // 16384 chunks
#define NBLOCKS (NCHUNK / WPB)     // 4096 blocks
#define HALO 256                   // carry horizon: (1-a)^256 <= 2e-12 for all alphas

typedef float f2 __attribute__((ext_vector_type(2)));

// ---- compile-time decay constants ----
constexpr double cpowi(double b, int e) { double r = 1.0; for (int i = 0; i < e; ++i) r *= b; return r; }
constexpr float tof(double x) { return (x < 1.2e-38 && x > -1.2e-38) ? 0.0f : (float)x; }

// Delta-space EMA: du_j = W*du_{j-1} + dx_j  (W = 1-alpha); pd = alpha*du.
// (p,t) packed as float2 -> v_pk_fma_f32: identical ops+constants on both.
#define W0f 0.9f
#define W1f 0.7f
#define W2f 0.4f
#define SE0 0.2f               // 2*alpha (we accumulate 2*h; 0.5 folded into final weights)
#define SE1 0.6f
#define SE2 1.2f
constexpr float NA0 = -(0.1f * 0.1f);   // -alpha^2
constexpr float NA1 = -(0.3f * 0.3f);
constexpr float NA2 = -(0.6f * 0.6f);

// main Kogge-Stone (lane spacing 16); sub-noise steps pruned (validated r2-r10, absmax 0.0)
constexpr float D0_1 = tof(cpowi(0.9, 16)),  D0_2 = tof(cpowi(0.9, 32));
constexpr float D0_4 = tof(cpowi(0.9, 64)),  D0_8 = tof(cpowi(0.9, 128));
constexpr float D1_1 = tof(cpowi(0.7, 16)),  D1_2 = tof(cpowi(0.7, 32));
constexpr float D2_1 = tof(cpowi(0.4, 16));
// halo Kogge-Stone (lane spacing 4)
constexpr float H0_1 = tof(cpowi(0.9, 4)),   H0_2 = tof(cpowi(0.9, 8));
constexpr float H0_4 = tof(cpowi(0.9, 16)),  H0_8 = tof(cpowi(0.9, 32));
constexpr float H0_16 = tof(cpowi(0.9, 64)), H0_32 = tof(cpowi(0.9, 128));
constexpr float H1_1 = tof(cpowi(0.7, 4)),   H1_2 = tof(cpowi(0.7, 8));
constexpr float H1_4 = tof(cpowi(0.7, 16)),  H1_8 = tof(cpowi(0.7, 32));
constexpr float H1_16 = tof(cpowi(0.7, 64));
constexpr float H2_1 = tof(cpowi(0.4, 4)),   H2_2 = tof(cpowi(0.4, 8));
constexpr float H2_4 = tof(cpowi(0.4, 16));

// log2(1-alpha): chunk carry fold weights (1-a)^(16*lane) = exp2(16*lane*log2(1-a))
#define L2_0 (-0.15200309344504997f)
#define L2_1 (-0.51457317282975830f)
#define L2_2 (-1.32192809488736230f)

__device__ __forceinline__ f2 bc(float s) { f2 r; r.x = s; r.y = s; return r; }
__device__ __forceinline__ f2 pfma(f2 a, f2 b, f2 c) { return a * b + c; }  // fp-contract -> v_pk_fma_f32
__device__ __forceinline__ f2 shfl_up2(f2 v, int d) {
    f2 r; r.x = __shfl_up(v.x, d); r.y = __shfl_up(v.y, d); return r;
}
__device__ __forceinline__ f2 shfl2(f2 v, int l) {
    f2 r; r.x = __shfl(v.x, l); r.y = __shfl(v.y, l); return r;
}

// packed Kogge-Stone step: v += (lane>=off ? d : 0) * shfl_up(v, off)
#define PSTEP(v, off, d)                                   \
    {                                                       \
        f2 _u = shfl_up2(v, off);                           \
        float _s = (lane >= off) ? d : 0.0f;                \
        v = pfma(bc(_s), _u, v);                            \
    }

__global__ void __launch_bounds__(TPB, 5) msl_main(const float* __restrict__ pred,
                                                   const float* __restrict__ targ,
                                                   float* __restrict__ partial) {
    const int lane = threadIdx.x & 63;
    const int wave = threadIdx.x >> 6;
    const int gcid = blockIdx.x * WPB + wave;   // global chunk id
    const int row  = gcid >> 3;                 // / CPR
    const int cid  = gcid & (CPR - 1);
    const float* __restrict__ prow = pred + (size_t)row * S_LEN;
    const float* __restrict__ trow = targ + (size_t)row * S_LEN;
    const int co   = cid * CHUNK;
    const int base = co + lane * PER_LANE;

    // dx scratch as float2 (j>=1; j=0 in regs): b64 DS ops halve the staging
    // DS count vs r7. Layout [j][lane]: wave b64 access = 512B = exactly 4
    // bank-passes, uniform -> conflict-free (r6/r7 measured 0 conflicts).
    __shared__ f2 dxs[WPB][PER_LANE - 1][64];   // 30720 B
    __shared__ float sred[WPB];

    const bool lz     = (lane == 0);
    const bool haloed = (cid != 0);
    const bool head   = (!haloed) && lz;   // owns global element 0 of the row

    // ---- chunk load, packed (p,t) ----
    f2 x2[PER_LANE];
    {
        const float4* p4 = reinterpret_cast<const float4*>(prow + base);
        const float4* t4 = reinterpret_cast<const float4*>(trow + base);
#pragma unroll
        for (int q = 0; q < PER_LANE / 4; ++q) {
            float4 a = p4[q];
            float4 b = t4[q];
            x2[4 * q + 0].x = a.x; x2[4 * q + 0].y = b.x;
            x2[4 * q + 1].x = a.y; x2[4 * q + 1].y = b.y;
            x2[4 * q + 2].x = a.z; x2[4 * q + 2].y = b.z;
            x2[4 * q + 3].x = a.w; x2[4 * q + 3].y = b.w;
        }
    }

    // ---- halo: recompute the delta-EMA carry from the preceding 256 elements
    // (truncation weight (1-a)^256 <= 2e-12; validated r7/r9/r10, absmax 0.0). ----
    f2 C0 = bc(0.f), C1 = bc(0.f), C2 = bc(0.f);
    f2 last2 = x2[0];                     // row-start default => dx_0 = 0 (head)
    if (haloed) {                          // wave-uniform branch
        f2 h2[4];
        {
            float4 a = *reinterpret_cast<const float4*>(prow + co - HALO + lane * 4);
            float4 b = *reinterpret_cast<const float4*>(trow + co - HALO + lane * 4);
            h2[0].x = a.x; h2[0].y = b.x;
            h2[1].x = a.y; h2[1].y = b.y;
            h2[2].x = a.z; h2[2].y = b.z;
            h2[3].x = a.w; h2[3].y = b.w;
        }
        f2 ph2 = shfl_up2(h2[3], 1);
        if (lz) ph2 = h2[0];               // oldest halo dx := 0 (weight ~0)

        f2 A0 = bc(0.f), A1 = bc(0.f), A2 = bc(0.f);
#pragma unroll
        for (int s = 0; s < 4; ++s) {
            f2 dx2 = h2[s] - ph2; ph2 = h2[s];
            A0 = pfma(bc(W0f), A0, dx2);
            A1 = pfma(bc(W1f), A1, dx2);
            A2 = pfma(bc(W2f), A2, dx2);
        }
        // packed halo scans (spacing 4, pruned per alpha)
        PSTEP(A0, 1, H0_1) PSTEP(A0, 2, H0_2) PSTEP(A0, 4, H0_4)
        PSTEP(A0, 8, H0_8) PSTEP(A0, 16, H0_16) PSTEP(A0, 32, H0_32)
        PSTEP(A1, 1, H1_1) PSTEP(A1, 2, H1_2) PSTEP(A1, 4, H1_4)
        PSTEP(A1, 8, H1_8) PSTEP(A1, 16, H1_16)
        PSTEP(A2, 1, H2_1) PSTEP(A2, 2, H2_2) PSTEP(A2, 4, H2_4)
        C0 = shfl2(A0, 63);
        C1 = shfl2(A1, 63);
        C2 = shfl2(A2, 63);
        last2 = shfl2(h2[3], 63);          // element co-1, for lane 0's first dx
    }

    // chunk dx boundary: lane l's previous element
    f2 pv2 = shfl_up2(x2[PER_LANE - 1], 1);
    if (lz) pv2 = last2;                   // head case already folded into last2

    // ---- pass 1: dx, stage dx (j>=1 to LDS as b64, j=0 in regs), packed du-EMA ----
    f2 dx0;
    f2 M0 = bc(0.f), M1 = bc(0.f), M2 = bc(0.f);
    f2 pp = pv2;
#pragma unroll
    for (int j = 0; j < PER_LANE; ++j) {
        f2 dx2 = x2[j] - pp; pp = x2[j];
        if (j == 0) dx0 = dx2;
        else        dxs[wave][j - 1][lane] = dx2;
        M0 = pfma(bc(W0f), M0, dx2);
        M1 = pfma(bc(W1f), M1, dx2);
        M2 = pfma(bc(W2f), M2, dx2);
    }
    // x dead from here.

    // ---- main packed scans (spacing 16, pruned) ----
    PSTEP(M0, 1, D0_1) PSTEP(M0, 2, D0_2) PSTEP(M0, 4, D0_4) PSTEP(M0, 8, D0_8)
    PSTEP(M1, 1, D1_1) PSTEP(M1, 2, D1_2)
    PSTEP(M2, 1, D2_1)

    // exclusive carry with halo fold: y_l = (l==0) ? C : v_{l-1} + (1-a)^(16l)*C
    const float e  = (float)(PER_LANE * lane);
    const float G0 = exp2f(e * L2_0);
    const float G1 = exp2f(e * L2_1);
    const float G2 = exp2f(e * L2_2);

    f2 u0 = shfl_up2(M0, 1), u1 = shfl_up2(M1, 1), u2 = shfl_up2(M2, 1);
    f2 y0 = lz ? C0 : pfma(bc(G0), C0, u0);
    f2 y1 = lz ? C1 : pfma(bc(G1), C1, u1);
    f2 y2 = lz ? C2 : pfma(bc(G2), C2, u2);

    // ---- pass 2: du = pk_fma(W, du, dx); huber on scaled deltas.
    // pd = a*du.x, td = a*du.y: dir<0 <=> du.x*du.y<0 ; se = a|du.x-du.y| ;
    // quad = 0.5*max(1 - a^2*du.x*du.y, 0)^2. Accumulate 2*h. ----
    float acc0 = 0.f, acc1 = 0.f, acc2 = 0.f;
    const float skip = head ? 0.0f : 1.0f;   // no loss term for the row's t=0
#pragma unroll
    for (int j = 0; j < PER_LANE; ++j) {
        f2 dx2 = (j == 0) ? dx0 : dxs[wave][j - 1][lane];
        y0 = pfma(bc(W0f), y0, dx2);
        y1 = pfma(bc(W1f), y1, dx2);
        y2 = pfma(bc(W2f), y2, dx2);

        float m0 = y0.x * y0.y, m1 = y1.x * y1.y, m2 = y2.x * y2.y;
        float se0 = SE0 * fabsf(y0.x - y0.y);
        float se1 = SE1 * fabsf(y1.x - y1.y);
        float se2 = SE2 * fabsf(y2.x - y2.y);
        float mm0 = fmaxf(fmaf(NA0, m0, 1.0f), 0.0f);
        float mm1 = fmaxf(fmaf(NA1, m1, 1.0f), 0.0f);
        float mm2 = fmaxf(fmaf(NA2, m2, 1.0f), 0.0f);
        float h0 = (m0 < 0.0f) ? se0 : mm0 * mm0;
        float h1 = (m1 < 0.0f) ? se1 : mm1 * mm1;
        float h2 = (m2 < 0.0f) ? se2 : mm2 * mm2;
        if (j == 0) { h0 *= skip; h1 *= skip; h2 *= skip; }
        acc0 += h0; acc1 += h1; acc2 += h2;
    }

    // accumulated 2*h -> weights 0.5*{0.5,0.3,0.2}; wave reduce; tiny block sum
    float wacc = 0.25f * acc0 + 0.15f * acc1 + 0.10f * acc2;
#pragma unroll
    for (int o = 32; o > 0; o >>= 1) wacc += __shfl_down(wacc, o);

    if (lz) sred[wave] = wacc;
    __syncthreads();   // the ONLY barrier, at kernel end
    if (threadIdx.x == 0)
        partial[blockIdx.x] = sred[0] + sred[1] + sred[2] + sred[3];
}

__global__ void __launch_bounds__(256) msl_reduce(const float* __restrict__ partial,
                                                  float* __restrict__ out) {
    const int tid = threadIdx.x;
    float v = 0.f;
#pragma unroll
    for (int k = 0; k < NBLOCKS / 256; ++k) v += partial[tid + 256 * k];
#pragma unroll
    for (int o = 32; o > 0; o >>= 1) v += __shfl_down(v, o);
    __shared__ float s[4];
    if ((tid & 63) == 0) s[tid >> 6] = v;
    __syncthreads();
    if (tid == 0)
        out[0] = (s[0] + s[1] + s[2] + s[3]) *
                 (float)(1.0 / ((double)(S_LEN - 1) * (double)B_ROWS));
}

extern "C" void kernel_launch(void* const* d_in, const int* in_sizes, int n_in,
                              void* d_out, int out_size, void* d_ws, size_t ws_size,
                              hipStream_t stream) {
    const float* pred = (const float*)d_in[0];
    const float* targ = (const float*)d_in[1];
    float* out = (float*)d_out;
    float* partial = (float*)d_ws;  // 4096 floats = 16 KB

    msl_main<<<NBLOCKS, TPB, 0, stream>>>(pred, targ, partial);
    msl_reduce<<<1, 256, 0, stream>>>(partial, out);
}